// Round 15
// baseline (29.599 us; speedup 1.0000x reference)
//
#include <hip/hip_runtime.h>

// DependencyGenerator, R15: single-pass fused kernel — every output cell
// written EXACTLY ONCE (no fill-then-scatter, no drain barrier, no RMW on
// evicted lines). Block b = (row=b>>2, qtr=b&3) owns a contiguous 256 KB
// quarter-row. Pre-store phases (all LDS/VALU + small reads):
//   A: stage emb table + own row's 511 entries; zero bitmap/hash
//   B: owned entries -> LDS hash (atomicCAS slot, atomicMax pack=k<<16|idxlow
//      => max-k = numpy last-dup-wins) + atomicOr 64Kbit cell bitmap
//   C: winning entry writes its value into h_val[slot]
//   D: fill loop: per float4 read a 4-bit nibble from the bitmap;
//      0 -> store ones (99.6%), else compose from h_val. Kernel ends when
//      stores drain — no post-barrier, no second store to any line.

#define SEQ_L   512
#define LM1     511
#define ROWELEM (SEQ_L * SEQ_L)      // 262144 floats per row
#define QUART   (ROWELEM / 4)        // 65536 floats (2^16) per block
#define NT      256
#define HSLOTS  512                  // ~128 owned keys -> load 0.25
#define NEMBMAX 64
#define BMWORDS (QUART / 32)         // 2048 u32 = 8 KB bitmap

typedef float vfloat4 __attribute__((ext_vector_type(4)));

__device__ __forceinline__ unsigned hash_key(unsigned key) {
    return (key * 2654435761u) >> 23;            // 9 bits
}

__global__ __launch_bounds__(NT) void depmask_onewrite(
    const int*   __restrict__ dep_i,
    const int*   __restrict__ dep_j,
    const int*   __restrict__ dep_type,
    const float* __restrict__ dep_emb,
    float*       __restrict__ out,
    int nemb)
{
    __shared__ unsigned bm[BMWORDS];
    __shared__ int      h_key[HSLOTS];
    __shared__ unsigned h_pack[HSLOTS];
    __shared__ float    h_val[HSLOTS];
    __shared__ float    s_emb[NEMBMAX];

    const int b   = blockIdx.x;
    const int row = b >> 2;
    const int qtr = b & 3;
    const int t   = threadIdx.x;

    // Phase A: all global reads + LDS init up front (no store queue yet).
    if (t < nemb) s_emb[t] = dep_emb[t];
    #pragma unroll
    for (int w = t; w < BMWORDS; w += NT) bm[w] = 0u;
    #pragma unroll
    for (int s = t; s < HSLOTS; s += NT) { h_key[s] = -1; h_pack[s] = 0; }

    const int base = row * LM1;
    const int k0 = t, k1 = t + NT;
    const int idx0 = dep_i[base + k0] * SEQ_L + dep_j[base + k0];
    const int ty0  = dep_type[base + k0];
    int idx1 = -1, ty1 = 0;
    if (k1 < LM1) {
        idx1 = dep_i[base + k1] * SEQ_L + dep_j[base + k1];
        ty1  = dep_type[base + k1];
    }
    __syncthreads();

    const float val0 = s_emb[ty0];
    const float val1 = (idx1 >= 0) ? s_emb[ty1] : 0.f;
    const bool own0 = (idx0 >> 16) == qtr;
    const bool own1 = idx1 >= 0 && ((idx1 >> 16) == qtr);
    const unsigned key0 = (unsigned)idx0 & 0xFFFFu;
    const unsigned key1 = (unsigned)idx1 & 0xFFFFu;
    const unsigned pk0  = ((unsigned)k0 << 16) | key0;
    const unsigned pk1  = ((unsigned)k1 << 16) | key1;

    // Phase B: hash insert + bitmap mark for owned entries (LDS-only).
    if (own0) {
        unsigned s = hash_key(key0);
        while (true) {
            int prev = atomicCAS(&h_key[s], -1, (int)key0);
            if (prev == -1 || prev == (int)key0) { atomicMax(&h_pack[s], pk0); break; }
            s = (s + 1) & (HSLOTS - 1);
        }
        atomicOr(&bm[key0 >> 5], 1u << (key0 & 31u));
    }
    if (own1) {
        unsigned s = hash_key(key1);
        while (true) {
            int prev = atomicCAS(&h_key[s], -1, (int)key1);
            if (prev == -1 || prev == (int)key1) { atomicMax(&h_pack[s], pk1); break; }
            s = (s + 1) & (HSLOTS - 1);
        }
        atomicOr(&bm[key1 >> 5], 1u << (key1 & 31u));
    }
    __syncthreads();

    // Phase C: the winning entry (max k per key) deposits its value.
    if (own0) {
        unsigned s = hash_key(key0);
        while (h_key[s] != (int)key0) s = (s + 1) & (HSLOTS - 1);
        if (h_pack[s] == pk0) h_val[s] = val0;
    }
    if (own1) {
        unsigned s = hash_key(key1);
        while (h_key[s] != (int)key1) s = (s + 1) & (HSLOTS - 1);
        if (h_pack[s] == pk1) h_val[s] = val1;
    }
    __syncthreads();

    // Phase D: single-pass fill. Thread t, iter it -> f4 index it*NT+t,
    // cells c = it*1024+4t .. +3. Bitmap word it*32+(t>>3) (32 consecutive
    // words/wave: conflict-free; 8-lane broadcast), nibble 4*(t&7).
    vfloat4* o4 = reinterpret_cast<vfloat4*>(out)
                + (size_t)row * (ROWELEM / 4) + (size_t)qtr * (QUART / 4);
    const vfloat4 ones = {1.f, 1.f, 1.f, 1.f};
    #pragma unroll 4
    for (int it = 0; it < QUART / 4 / NT; ++it) {        // 64 iterations
        const unsigned wbits = bm[it * 32 + (t >> 3)];
        const unsigned nib = (wbits >> (4 * (t & 7))) & 0xFu;
        vfloat4 v = ones;
        if (nib) {                                       // rare (~0.4%)
            const unsigned cbase = (unsigned)(it * 1024 + 4 * t);
            #pragma unroll
            for (int j = 0; j < 4; ++j) {
                if (nib & (1u << j)) {
                    const unsigned key = cbase + j;
                    unsigned s = hash_key(key);
                    while (h_key[s] != (int)key) s = (s + 1) & (HSLOTS - 1);
                    v[j] = h_val[s];
                }
            }
        }
        o4[it * NT + t] = v;
    }
}

extern "C" void kernel_launch(void* const* d_in, const int* in_sizes, int n_in,
                              void* d_out, int out_size, void* d_ws, size_t ws_size,
                              hipStream_t stream) {
    const int*   dep_i    = (const int*)  d_in[0];
    const int*   dep_j    = (const int*)  d_in[1];
    const int*   dep_type = (const int*)  d_in[2];
    // d_in[3] = seq_len scalar (512)
    const float* dep_emb  = (const float*)d_in[4];
    float*       out      = (float*)      d_out;

    const int rows = in_sizes[0] / LM1;          // 128
    const int nemb = in_sizes[4];                // 53

    depmask_onewrite<<<dim3(4 * rows), dim3(NT), 0, stream>>>(
        dep_i, dep_j, dep_type, dep_emb, out, nemb);
}

// Round 16
// 27.663 us; speedup vs baseline: 1.0700x; 1.0700x over previous
//
#include <hip/hip_runtime.h>

// DependencyGenerator, FINAL (= R13, best measured: 27.8 us).
// ONE kernel, ownership fusion, reads-before-stores.
// Block b = (row r = b>>1, half h = b&1). Phase order is the whole trick:
//   A: load emb table (53 f) + this row's 511 (i,j,type) -> regs/LDS
//   B: __syncthreads (cheap; no big store queue yet)
//   C: fill own half-row: 512 KB contiguous, 128 float4 stores/thread
//   D: LDS-hash insert of own-half entries — pure LDS/VALU, NO vmem use,
//      so it genuinely overlaps the store drain (R12 died on vmcnt FIFO:
//      loads after stores can't complete until the stores drain).
//   E: __syncthreads -> own fill stores complete; targets idx>>17==h are
//      block-exclusive, so no cross-block ordering needed.
//   F: winners (atomicMax pack = k<<17|idxlow -> numpy last-dup-wins) store.
// Ceiling: two-point fit vs rocclr memset (536.9MB@79us) gives steady
// 7.57 TB/s + ramp 8.1us -> floor 25.8us dispatch; R13 measures exactly
// that. Remaining ~2us = graph replay overhead. At the store roofline.

#define SEQ_L   512
#define LM1     511
#define ROWELEM (SEQ_L * SEQ_L)      // 262144 floats per row
#define HALF    (ROWELEM / 2)        // 131072 floats (2^17)
#define NT      256
#define HSLOTS  1024                 // ~256 keys -> load 0.25
#define NEMBMAX 64

typedef float vfloat4 __attribute__((ext_vector_type(4)));

__device__ __forceinline__ unsigned hash_key(unsigned key) {
    return (key * 2654435761u) >> 22;            // 10 bits
}

__global__ __launch_bounds__(NT) void depmask_fused(
    const int*   __restrict__ dep_i,
    const int*   __restrict__ dep_j,
    const int*   __restrict__ dep_type,
    const float* __restrict__ dep_emb,
    float*       __restrict__ out,
    int nemb)
{
    __shared__ int      h_key[HSLOTS];
    __shared__ unsigned h_pack[HSLOTS];
    __shared__ float    s_emb[NEMBMAX];

    const int b   = blockIdx.x;
    const int row = b >> 1;
    const int hlf = b & 1;
    const int t   = threadIdx.x;

    // Phase A: all global reads up front.
    if (t < nemb) s_emb[t] = dep_emb[t];
    #pragma unroll
    for (int s = t; s < HSLOTS; s += NT) { h_key[s] = -1; h_pack[s] = 0; }

    const int base = row * LM1;
    const int k0 = t, k1 = t + NT;
    const int idx0 = dep_i[base + k0] * SEQ_L + dep_j[base + k0];
    const int ty0  = dep_type[base + k0];
    int idx1 = -1, ty1 = 0;
    if (k1 < LM1) {
        idx1 = dep_i[base + k1] * SEQ_L + dep_j[base + k1];
        ty1  = dep_type[base + k1];
    }

    // Phase B: table/hash-init visible; staged loads complete (small).
    __syncthreads();

    const float val0 = s_emb[ty0];
    const float val1 = (idx1 >= 0) ? s_emb[ty1] : 0.f;

    // Phase C: fill own half-row (contiguous 512 KB; 128 f4 stores/thread).
    {
        const vfloat4 ones = {1.f, 1.f, 1.f, 1.f};
        vfloat4* o4 = reinterpret_cast<vfloat4*>(out)
                    + (size_t)row * (ROWELEM / 4) + (size_t)hlf * (HALF / 4);
        #pragma unroll 4
        for (int it = 0; it < HALF / 4 / NT; ++it)     // 128 stores
            o4[it * NT + t] = ones;
    }

    // Phase D: hash-insert own-half entries (LDS/VALU only -> overlaps drain).
    if ((idx0 >> 17) == hlf) {
        const unsigned key = (unsigned)idx0 & 0x1FFFFu;
        const unsigned pack = ((unsigned)k0 << 17) | key;
        unsigned s = hash_key(key);
        while (true) {
            int prev = atomicCAS(&h_key[s], -1, (int)key);
            if (prev == -1 || prev == (int)key) { atomicMax(&h_pack[s], pack); break; }
            s = (s + 1) & (HSLOTS - 1);
        }
    }
    if (idx1 >= 0 && (idx1 >> 17) == hlf) {
        const unsigned key = (unsigned)idx1 & 0x1FFFFu;
        const unsigned pack = ((unsigned)k1 << 17) | key;
        unsigned s = hash_key(key);
        while (true) {
            int prev = atomicCAS(&h_key[s], -1, (int)key);
            if (prev == -1 || prev == (int)key) { atomicMax(&h_pack[s], pack); break; }
            s = (s + 1) & (HSLOTS - 1);
        }
    }

    // Phase E: drains own fill stores; hash stable.
    __syncthreads();

    // Phase F: winner-check (pack equality) -> scatter store own val.
    if ((idx0 >> 17) == hlf) {
        const unsigned key = (unsigned)idx0 & 0x1FFFFu;
        const unsigned pack = ((unsigned)k0 << 17) | key;
        unsigned s = hash_key(key);
        while (h_key[s] != (int)key) s = (s + 1) & (HSLOTS - 1);
        if (h_pack[s] == pack) out[(size_t)row * ROWELEM + idx0] = val0;
    }
    if (idx1 >= 0 && (idx1 >> 17) == hlf) {
        const unsigned key = (unsigned)idx1 & 0x1FFFFu;
        const unsigned pack = ((unsigned)k1 << 17) | key;
        unsigned s = hash_key(key);
        while (h_key[s] != (int)key) s = (s + 1) & (HSLOTS - 1);
        if (h_pack[s] == pack) out[(size_t)row * ROWELEM + idx1] = val1;
    }
}

extern "C" void kernel_launch(void* const* d_in, const int* in_sizes, int n_in,
                              void* d_out, int out_size, void* d_ws, size_t ws_size,
                              hipStream_t stream) {
    const int*   dep_i    = (const int*)  d_in[0];
    const int*   dep_j    = (const int*)  d_in[1];
    const int*   dep_type = (const int*)  d_in[2];
    // d_in[3] = seq_len scalar (512)
    const float* dep_emb  = (const float*)d_in[4];
    float*       out      = (float*)      d_out;

    const int rows = in_sizes[0] / LM1;          // 128
    const int nemb = in_sizes[4];                // 53

    depmask_fused<<<dim3(2 * rows), dim3(NT), 0, stream>>>(
        dep_i, dep_j, dep_type, dep_emb, out, nemb);
}